// Round 2
// baseline (399.461 us; speedup 1.0000x reference)
//
#include <hip/hip_runtime.h>

// Problem constants (fixed by the reference setup)
#define BB   2
#define DD   96
#define HH   96
#define WW   96
#define CINC 16
#define COUTC 32
#define KVOL 27                        // 3*3*3
#define GRID_VOX (BB*DD*HH*WW)         // 1,769,472 voxels
#define NW (KVOL*CINC*COUTC)           // 13824 repacked weights

// Workspace layout:
//   [0 .. GRID_VOX*4)            : int32 idx grid (voxel -> point id, -1 = empty)
//   [GRID_VOX*4 .. +NW*4)        : repacked weights wr[kk][ci][co]
#define WR_OFFSET_BYTES (GRID_VOX * sizeof(int))

// Fused: scatter point ids into idx grid + repack weights [co][ci][kk]->[kk][ci][co]
__global__ __launch_bounds__(256) void setup_kernel(
        const int* __restrict__ idx, int* __restrict__ g,
        const float* __restrict__ w, float* __restrict__ wr,
        int n, int scatter_blocks) {
    if ((int)blockIdx.x < scatter_blocks) {
        int i = blockIdx.x * 256 + threadIdx.x;
        if (i >= n) return;
        int4 v = ((const int4*)idx)[i];   // (b, z, y, x)
        int lin = ((v.x * DD + v.y) * HH + v.z) * WW + v.w;
        g[lin] = i;
    } else {
        int t = ((int)blockIdx.x - scatter_blocks) * 256 + threadIdx.x;
        if (t >= NW) return;              // t = kk*512 + ci*32 + co
        int co = t & (COUTC - 1);
        int ci = (t >> 5) & (CINC - 1);
        int kk = t >> 9;
        wr[t] = w[(co * CINC + ci) * KVOL + kk];
    }
}

__device__ __forceinline__ void loadfeat(float f[CINC],
        const float* __restrict__ feat, int nid) {
    float4 a = make_float4(0.f, 0.f, 0.f, 0.f), b = a, c = a, d = a;
    if (nid >= 0) {
        const float4* p = (const float4*)(feat + (size_t)nid * CINC);
        a = p[0]; b = p[1]; c = p[2]; d = p[3];
    }
    f[0]=a.x;  f[1]=a.y;  f[2]=a.z;  f[3]=a.w;
    f[4]=b.x;  f[5]=b.y;  f[6]=b.z;  f[7]=b.w;
    f[8]=c.x;  f[9]=c.y;  f[10]=c.z; f[11]=c.w;
    f[12]=d.x; f[13]=d.y; f[14]=d.z; f[15]=d.w;
}

__device__ __forceinline__ void fmablock(float acc[COUTC], const float f[CINC],
        const float* __restrict__ wo) {
#pragma unroll
    for (int ci = 0; ci < CINC; ++ci) {
        float fv = f[ci];
#pragma unroll
        for (int co = 0; co < COUTC; ++co)
            acc[co] = fmaf(fv, wo[ci * COUTC + co], acc[co]);
    }
}

__global__ __launch_bounds__(256) void conv_gather_kernel(
        const float*  __restrict__ feat,
        const int*    __restrict__ idx,
        const float*  __restrict__ wr,     // [27][16][32], wave-uniform indexed
        const float*  __restrict__ bias,   // [32]
        const int*    __restrict__ g,
        float*        __restrict__ out,
        int n) {
    int i = blockIdx.x * blockDim.x + threadIdx.x;
    if (i >= n) return;

    int4 v = ((const int4*)idx)[i];   // b, z, y, x
    const int b = v.x, z = v.y, y = v.z, x = v.w;
    const int base = ((b * DD + z) * HH + y) * WW + x;

    // ---- Phase 1: probe all 27 neighbor ids (independent loads, one wait) ----
    int nid[KVOL];
#pragma unroll
    for (int kk = 0; kk < KVOL; ++kk) {
        int dz = kk / 9 - 1;
        int dy = (kk / 3) % 3 - 1;
        int dx = kk % 3 - 1;
        int nz = z + dz, ny = y + dy, nx = x + dx;
        bool inb = ((unsigned)nz < DD) & ((unsigned)ny < HH) & ((unsigned)nx < WW);
        int lin = base + (dz * HH + dy) * WW + dx;  // == neighbor lin when inb
        int val = g[inb ? lin : 0];                  // branchless clamped load
        nid[kk] = inb ? val : -1;
    }

    float acc[COUTC];
#pragma unroll
    for (int co = 0; co < COUTC; ++co) acc[co] = bias[co];

    // ---- Phase 2: ping-pong pipeline — load f[kk+1] while FMA-ing f[kk] ----
    float fa[CINC], fb[CINC];
    loadfeat(fa, feat, nid[0]);
#pragma unroll 1
    for (int kk = 0; kk < KVOL - 1; kk += 2) {       // kk = 0,2,...,24
        loadfeat(fb, feat, nid[kk + 1]);
        fmablock(acc, fa, wr + kk * (CINC * COUTC));
        loadfeat(fa, feat, nid[kk + 2]);             // kk+2 <= 26
        fmablock(acc, fb, wr + (kk + 1) * (CINC * COUTC));
    }
    fmablock(acc, fa, wr + (KVOL - 1) * (CINC * COUTC));

    float4* op = (float4*)(out + (size_t)i * COUTC);
#pragma unroll
    for (int q = 0; q < 8; ++q)
        op[q] = make_float4(acc[4*q], acc[4*q+1], acc[4*q+2], acc[4*q+3]);
}

extern "C" void kernel_launch(void* const* d_in, const int* in_sizes, int n_in,
                              void* d_out, int out_size, void* d_ws, size_t ws_size,
                              hipStream_t stream) {
    const float* feat  = (const float*)d_in[0];   // [N,16] fp32
    const int*   idx   = (const int*)d_in[1];     // [N,4]  int32
    const float* convw = (const float*)d_in[2];   // [32,16,3,3,3] fp32
    const float* convb = (const float*)d_in[3];   // [32] fp32
    float* out = (float*)d_out;

    const int n = in_sizes[1] / 4;                // 200000

    int*   g  = (int*)d_ws;
    float* wr = (float*)((char*)d_ws + WR_OFFSET_BYTES);

    // 1) idx grid = -1 (0xFF bytes == int -1), capture-legal async memset
    hipMemsetAsync(g, 0xFF, (size_t)GRID_VOX * sizeof(int), stream);

    // 2) fused scatter + weight repack
    const int sb = (n + 255) / 256;
    const int rb = (NW + 255) / 256;
    setup_kernel<<<sb + rb, 256, 0, stream>>>(idx, g, convw, wr, n, sb);

    // 3) gather-conv
    conv_gather_kernel<<<(n + 255) / 256, 256, 0, stream>>>(
        feat, idx, wr, convb, g, out, n);
}

// Round 3
// 298.010 us; speedup vs baseline: 1.3404x; 1.3404x over previous
//
#include <hip/hip_runtime.h>

// Problem constants (fixed by the reference setup)
#define BB   2
#define DD   96
#define HH   96
#define WW   96
#define CINC 16
#define COUTC 32
#define KVOL 27
#define GRID_VOX (BB*DD*HH*WW)         // 1,769,472 voxels
#define NW (KVOL*CINC*COUTC)           // 13824 repacked weights
#define VPT 8                          // voxels per thread in compact
#define CVB (256*VPT)                  // voxels per compact block = 2048

// ---------------- dispatch 1: scatter pids + repack weights + zero counter ---
__global__ __launch_bounds__(256) void setup_kernel(
        const int* __restrict__ idx, int* __restrict__ g,
        const float* __restrict__ w, float* __restrict__ wr,
        int* __restrict__ counter, int n, int scatter_blocks) {
    if ((int)blockIdx.x < scatter_blocks) {
        int i = blockIdx.x * 256 + threadIdx.x;
        if (i >= n) return;
        int4 v = ((const int4*)idx)[i];   // (b, z, y, x)
        int lin = ((v.x * DD + v.y) * HH + v.z) * WW + v.w;
        g[lin] = i;
    } else {
        int t = ((int)blockIdx.x - scatter_blocks) * 256 + threadIdx.x;
        if (t == 0) counter[0] = 0;
        if (t >= NW) return;              // t = kk*512 + ci*32 + co
        int co = t & (COUTC - 1);
        int ci = (t >> 5) & (CINC - 1);
        int kk = t >> 9;
        wr[t] = w[(co * CINC + ci) * KVOL + kk];
    }
}

// -------- dispatch 2: block-ordered compaction + in-place grid rewrite -------
// After this kernel: g[v] = sorted id j for active voxels, n for empty.
// featS[j] = feat[perm[j]]; pc[j] = packed coords; featS[n] = zero row.
// Robust to arbitrary ws garbage: entry accepted only if pid<n AND idx[pid]
// round-trips to this voxel.
__global__ __launch_bounds__(256) void compact_kernel(
        const int* __restrict__ idx, const float* __restrict__ feat,
        int* __restrict__ g, float* __restrict__ featS,
        int* __restrict__ pc, int* __restrict__ perm,
        int* __restrict__ counter, int n) {
    __shared__ int s_off[256];
    __shared__ int s_base;
    const int t = threadIdx.x;
    const int base = blockIdx.x * CVB + t * VPT;

    int4 a0 = ((const int4*)(g + base))[0];
    int4 a1 = ((const int4*)(g + base))[1];
    int vals[VPT] = {a0.x, a0.y, a0.z, a0.w, a1.x, a1.y, a1.z, a1.w};
    int pid[VPT], pck[VPT];
    int cnt = 0;
#pragma unroll
    for (int q = 0; q < VPT; ++q) {       // fully unrolled: static indices only
        int p = vals[q];
        bool ok = ((unsigned)p < (unsigned)n);
        int pk = 0;
        if (ok) {
            int4 c = ((const int4*)idx)[p];
            int lin = ((c.x * DD + c.y) * HH + c.z) * WW + c.w;
            ok = (lin == base + q);
            pk = (c.x << 21) | (c.y << 14) | (c.z << 7) | c.w;
        }
        pid[q] = ok ? p : -1;
        pck[q] = pk;
        cnt += ok ? 1 : 0;
    }

    s_off[t] = cnt;
    __syncthreads();
    for (int d = 1; d < 256; d <<= 1) {   // inclusive Hillis-Steele scan
        int v = (t >= d) ? s_off[t - d] : 0;
        __syncthreads();
        s_off[t] += v;
        __syncthreads();
    }
    if (t == 255) s_base = atomicAdd(counter, s_off[255]);
    __syncthreads();
    int o = s_base + s_off[t] - cnt;

#pragma unroll
    for (int q = 0; q < VPT; ++q) {
        int tag = n;                      // empty marker -> zero row
        int p = pid[q];
        if (p >= 0) {
            pc[o] = pck[q];
            perm[o] = p;
            const float4* src = (const float4*)(feat + (size_t)p * CINC);
            float4* dst = (float4*)(featS + (size_t)o * CINC);
            dst[0] = src[0]; dst[1] = src[1]; dst[2] = src[2]; dst[3] = src[3];
            tag = o;
            ++o;
        }
        g[base + q] = tag;
    }
    if (blockIdx.x == 0 && t == 0) {      // zero row at featS[n]
        float4 z4 = make_float4(0.f, 0.f, 0.f, 0.f);
        float4* zr = (float4*)(featS + (size_t)n * CINC);
        zr[0] = z4; zr[1] = z4; zr[2] = z4; zr[3] = z4;
    }
}

// ------------------------------- dispatch 3: conv ---------------------------
__device__ __forceinline__ void loadrow(float f[CINC],
        const float* __restrict__ featS, int nid) {
    const float4* p = (const float4*)(featS + (size_t)nid * CINC);
    float4 a = p[0], b = p[1], c = p[2], d = p[3];
    f[0]=a.x;  f[1]=a.y;  f[2]=a.z;  f[3]=a.w;
    f[4]=b.x;  f[5]=b.y;  f[6]=b.z;  f[7]=b.w;
    f[8]=c.x;  f[9]=c.y;  f[10]=c.z; f[11]=c.w;
    f[12]=d.x; f[13]=d.y; f[14]=d.z; f[15]=d.w;
}

__device__ __forceinline__ void fmablock(float acc[COUTC], const float f[CINC],
        const float* __restrict__ wo) {
#pragma unroll
    for (int ci = 0; ci < CINC; ++ci) {
        float fv = f[ci];
#pragma unroll
        for (int co = 0; co < COUTC; ++co)
            acc[co] = fmaf(fv, wo[ci * COUTC + co], acc[co]);
    }
}

__global__ __launch_bounds__(256) void conv_kernel(
        const float* __restrict__ featS, const int* __restrict__ pc,
        const int* __restrict__ perm, const float* __restrict__ wr,
        const float* __restrict__ bias, const int* __restrict__ g,
        float* __restrict__ out, int n) {
    int j = blockIdx.x * blockDim.x + threadIdx.x;
    if (j >= n) return;
    int p = pc[j];
    const int x = p & 127, y = (p >> 7) & 127, z = (p >> 14) & 127, b = p >> 21;
    const int base = ((b * DD + z) * HH + y) * WW + x;

    auto probe = [&](int kk) -> int {
        int dz = kk / 9 - 1;
        int dy = (kk / 3) % 3 - 1;
        int dx = kk - (kk / 3) * 3 - 1;
        int nz = z + dz, ny = y + dy, nx = x + dx;
        bool inb = ((unsigned)nz < DD) & ((unsigned)ny < HH) & ((unsigned)nx < WW);
        int lin = base + (dz * HH + dy) * WW + dx;
        int v = g[inb ? lin : 0];
        return inb ? v : n;               // OOB -> zero row
    };

    float acc[COUTC];
#pragma unroll
    for (int co = 0; co < COUTC; ++co) acc[co] = bias[co];

    // distance-2 pipeline, scalar rotation only (no indexed register arrays)
    int na = probe(0);
    int nb = probe(1);
    float fa[CINC];
    loadrow(fa, featS, na);
#pragma unroll 2
    for (int kk = 0; kk < KVOL - 1; ++kk) {          // kk = 0..25
        int nc = (kk < KVOL - 2) ? probe(kk + 2) : n;
        float fb[CINC];
        loadrow(fb, featS, nb);                      // in flight during fma
        fmablock(acc, fa, wr + kk * (CINC * COUTC));
#pragma unroll
        for (int q = 0; q < CINC; ++q) fa[q] = fb[q];
        na = nb; nb = nc;
    }
    fmablock(acc, fa, wr + (KVOL - 1) * (CINC * COUTC));

    float4* op = (float4*)(out + (size_t)perm[j] * COUTC);
#pragma unroll
    for (int q = 0; q < 8; ++q)
        op[q] = make_float4(acc[4*q], acc[4*q+1], acc[4*q+2], acc[4*q+3]);
}

extern "C" void kernel_launch(void* const* d_in, const int* in_sizes, int n_in,
                              void* d_out, int out_size, void* d_ws, size_t ws_size,
                              hipStream_t stream) {
    const float* feat  = (const float*)d_in[0];   // [N,16] fp32
    const int*   idx   = (const int*)d_in[1];     // [N,4]  int32
    const float* convw = (const float*)d_in[2];   // [32,16,3,3,3] fp32
    const float* convb = (const float*)d_in[3];   // [32] fp32
    float* out = (float*)d_out;

    const int n = in_sizes[1] / 4;                // 200000

    // workspace layout (16B-aligned regions)
    char* ws = (char*)d_ws;
    int*   g       = (int*)ws;                                  // 7,077,888 B
    float* wr      = (float*)(ws + GRID_VOX * 4);               //    55,296 B
    int*   counter = (int*)(ws + GRID_VOX * 4 + NW * 4);        //       256 B pad
    int*   pc      = (int*)(ws + GRID_VOX * 4 + NW * 4 + 256);
    int*   perm    = pc + n;
    float* featS   = (float*)(perm + n);                        // (n+1)*16 floats

    const int sb = (n + 255) / 256;
    const int rb = (NW + 255) / 256;
    setup_kernel<<<sb + rb, 256, 0, stream>>>(idx, g, convw, wr, counter, n, sb);
    compact_kernel<<<GRID_VOX / CVB, 256, 0, stream>>>(
        idx, feat, g, featS, pc, perm, counter, n);
    conv_kernel<<<(n + 255) / 256, 256, 0, stream>>>(
        featS, pc, perm, wr, convb, g, out, n);
}

// Round 4
// 296.281 us; speedup vs baseline: 1.3482x; 1.0058x over previous
//
#include <hip/hip_runtime.h>

// Problem constants (fixed by the reference setup)
#define BB   2
#define DD   96
#define HH   96
#define WW   96
#define CINC 16
#define COUTC 32
#define KVOL 27
#define GRID_VOX (BB*DD*HH*WW)         // 1,769,472 voxels
#define NW (KVOL*CINC*COUTC)           // 13824 repacked weights
#define VPT 8                          // voxels per thread in compact
#define CVB (256*VPT)                  // voxels per compact block = 2048

// Repacked weights in constant address space: uniform-offset reads compile to
// s_load -> SGPR operands for v_fma (no VGPRs, no VMEM issue slots).
__constant__ float wc[NW];

// ---------------- dispatch 1: scatter pids + repack weights + zero counter ---
__global__ __launch_bounds__(256) void setup_kernel(
        const int* __restrict__ idx, int* __restrict__ g,
        const float* __restrict__ w, float* __restrict__ wrp,
        int* __restrict__ counter, int n, int scatter_blocks) {
    if ((int)blockIdx.x < scatter_blocks) {
        int i = blockIdx.x * 256 + threadIdx.x;
        if (i >= n) return;
        int4 v = ((const int4*)idx)[i];   // (b, z, y, x)
        int lin = ((v.x * DD + v.y) * HH + v.z) * WW + v.w;
        g[lin] = i;
    } else {
        int t = ((int)blockIdx.x - scatter_blocks) * 256 + threadIdx.x;
        if (t == 0) counter[0] = 0;
        if (t >= NW) return;              // t = kk*512 + ci*32 + co
        int co = t & (COUTC - 1);
        int ci = (t >> 5) & (CINC - 1);
        int kk = t >> 9;
        wrp[t] = w[(co * CINC + ci) * KVOL + kk];  // wrp = &wc (symbol addr)
    }
}

// -------- dispatch 2: block-ordered compaction + in-place grid rewrite -------
// After: g[v] = sorted id j for active voxels, n for empty. featS[j] =
// feat[perm[j]]; pc[j] = packed coords; featS[n] = zero row. Robust to ws
// garbage: entry accepted only if pid<n AND idx[pid] round-trips to voxel.
__global__ __launch_bounds__(256) void compact_kernel(
        const int* __restrict__ idx, const float* __restrict__ feat,
        int* __restrict__ g, float* __restrict__ featS,
        int* __restrict__ pc, int* __restrict__ perm,
        int* __restrict__ counter, int n) {
    __shared__ int s_off[256];
    __shared__ int s_base;
    const int t = threadIdx.x;
    const int base = blockIdx.x * CVB + t * VPT;

    int4 a0 = ((const int4*)(g + base))[0];
    int4 a1 = ((const int4*)(g + base))[1];
    int vals[VPT] = {a0.x, a0.y, a0.z, a0.w, a1.x, a1.y, a1.z, a1.w};
    int pid[VPT], pck[VPT];
    int cnt = 0;
#pragma unroll
    for (int q = 0; q < VPT; ++q) {       // fully unrolled: static indices only
        int p = vals[q];
        bool ok = ((unsigned)p < (unsigned)n);
        int pk = 0;
        if (ok) {
            int4 c = ((const int4*)idx)[p];
            int lin = ((c.x * DD + c.y) * HH + c.z) * WW + c.w;
            ok = (lin == base + q);
            pk = (c.x << 21) | (c.y << 14) | (c.z << 7) | c.w;
        }
        pid[q] = ok ? p : -1;
        pck[q] = pk;
        cnt += ok ? 1 : 0;
    }

    s_off[t] = cnt;
    __syncthreads();
    for (int d = 1; d < 256; d <<= 1) {   // inclusive Hillis-Steele scan
        int v = (t >= d) ? s_off[t - d] : 0;
        __syncthreads();
        s_off[t] += v;
        __syncthreads();
    }
    if (t == 255) s_base = atomicAdd(counter, s_off[255]);
    __syncthreads();
    int o = s_base + s_off[t] - cnt;

#pragma unroll
    for (int q = 0; q < VPT; ++q) {
        int tag = n;                      // empty marker -> zero row
        int p = pid[q];
        if (p >= 0) {
            pc[o] = pck[q];
            perm[o] = p;
            const float4* src = (const float4*)(feat + (size_t)p * CINC);
            float4* dst = (float4*)(featS + (size_t)o * CINC);
            dst[0] = src[0]; dst[1] = src[1]; dst[2] = src[2]; dst[3] = src[3];
            tag = o;
            ++o;
        }
        g[base + q] = tag;
    }
    if (blockIdx.x == 0 && t == 0) {      // zero row at featS[n]
        float4 z4 = make_float4(0.f, 0.f, 0.f, 0.f);
        float4* zr = (float4*)(featS + (size_t)n * CINC);
        zr[0] = z4; zr[1] = z4; zr[2] = z4; zr[3] = z4;
    }
}

// ------------------------------- dispatch 3: conv ---------------------------
__device__ __forceinline__ void loadrow(float f[CINC],
        const float* __restrict__ featS, int nid) {
    const float4* p = (const float4*)(featS + (size_t)nid * CINC);
    float4 a = p[0], b = p[1], c = p[2], d = p[3];
    f[0]=a.x;  f[1]=a.y;  f[2]=a.z;  f[3]=a.w;
    f[4]=b.x;  f[5]=b.y;  f[6]=b.z;  f[7]=b.w;
    f[8]=c.x;  f[9]=c.y;  f[10]=c.z; f[11]=c.w;
    f[12]=d.x; f[13]=d.y; f[14]=d.z; f[15]=d.w;
}

// Weights from wc[] (constant AS, uniform kbase) -> SGPR operands.
__device__ __forceinline__ void fmablock(float acc[COUTC], const float f[CINC],
        int kbase) {
#pragma unroll
    for (int ci = 0; ci < CINC; ++ci) {
        float fv = f[ci];
#pragma unroll
        for (int co = 0; co < COUTC; ++co)
            acc[co] = fmaf(fv, wc[kbase + ci * COUTC + co], acc[co]);
    }
}

__global__ __launch_bounds__(256, 4) void conv_kernel(
        const float* __restrict__ featS, const int* __restrict__ pc,
        const int* __restrict__ perm,
        const float* __restrict__ bias, const int* __restrict__ g,
        float* __restrict__ out, int n) {
    int j = blockIdx.x * blockDim.x + threadIdx.x;
    if (j >= n) return;
    int p = pc[j];
    const int x = p & 127, y = (p >> 7) & 127, z = (p >> 14) & 127, b = p >> 21;
    const int base = ((b * DD + z) * HH + y) * WW + x;

    auto probe = [&](int kk) -> int {
        int dz = kk / 9 - 1;
        int dy = (kk / 3) % 3 - 1;
        int dx = kk - (kk / 3) * 3 - 1;
        int nz = z + dz, ny = y + dy, nx = x + dx;
        bool inb = ((unsigned)nz < DD) & ((unsigned)ny < HH) & ((unsigned)nx < WW);
        int lin = base + (dz * HH + dy) * WW + dx;
        int v = g[inb ? lin : 0];
        return inb ? v : n;               // OOB -> zero row
    };

    float acc[COUTC];
#pragma unroll
    for (int co = 0; co < COUTC; ++co) acc[co] = bias[co];

    // Copy-free ping-pong: pair-unrolled kk loop, fa/fb alternate by name.
    int n0 = probe(0);
    int nb = probe(1);
    float fa[CINC], fb[CINC];
    loadrow(fa, featS, n0);
#pragma unroll 1
    for (int kk = 0; kk < KVOL - 1; kk += 2) {       // kk = 0,2,...,24
        loadrow(fb, featS, nb);                      // row kk+1 in flight
        int nc = probe(kk + 2);                      // id for row kk+2
        fmablock(acc, fa, kk * (CINC * COUTC));      // consume row kk
        int nbn = (kk + 3 < KVOL) ? probe(kk + 3) : n;
        loadrow(fa, featS, nc);                      // row kk+2 in flight
        fmablock(acc, fb, (kk + 1) * (CINC * COUTC));// consume row kk+1
        nb = nbn;
    }
    fmablock(acc, fa, (KVOL - 1) * (CINC * COUTC));  // row 26

    float4* op = (float4*)(out + (size_t)perm[j] * COUTC);
#pragma unroll
    for (int q = 0; q < 8; ++q)
        op[q] = make_float4(acc[4*q], acc[4*q+1], acc[4*q+2], acc[4*q+3]);
}

extern "C" void kernel_launch(void* const* d_in, const int* in_sizes, int n_in,
                              void* d_out, int out_size, void* d_ws, size_t ws_size,
                              hipStream_t stream) {
    const float* feat  = (const float*)d_in[0];   // [N,16] fp32
    const int*   idx   = (const int*)d_in[1];     // [N,4]  int32
    const float* convw = (const float*)d_in[2];   // [32,16,3,3,3] fp32
    const float* convb = (const float*)d_in[3];   // [32] fp32
    float* out = (float*)d_out;

    const int n = in_sizes[1] / 4;                // 200000

    // workspace layout (16B-aligned regions)
    char* ws = (char*)d_ws;
    int*   g       = (int*)ws;                                  // 7,077,888 B
    int*   counter = (int*)(ws + GRID_VOX * 4);                 //       256 B pad
    int*   pc      = (int*)(ws + GRID_VOX * 4 + 256);
    int*   perm    = pc + n;
    float* featS   = (float*)(perm + n);                        // (n+1)*16 floats

    // Device address of the __constant__ weight array (host-side query; no
    // stream op -> graph-capture safe).
    void* wc_addr = nullptr;
    hipGetSymbolAddress(&wc_addr, HIP_SYMBOL(wc));
    float* wrp = (float*)wc_addr;

    // 1) idx grid = -1 (0xFF bytes == int -1), capture-legal async memset
    hipMemsetAsync(g, 0xFF, (size_t)GRID_VOX * sizeof(int), stream);

    const int sb = (n + 255) / 256;
    const int rb = (NW + 255) / 256;
    setup_kernel<<<sb + rb, 256, 0, stream>>>(idx, g, convw, wrp, counter, n, sb);
    compact_kernel<<<GRID_VOX / CVB, 256, 0, stream>>>(
        idx, feat, g, featS, pc, perm, counter, n);
    conv_kernel<<<(n + 255) / 256, 256, 0, stream>>>(
        featS, pc, perm, convb, g, out, n);
}

// Round 5
// 127.919 us; speedup vs baseline: 3.1228x; 2.3162x over previous
//
#include <hip/hip_runtime.h>

// Problem constants (fixed by the reference setup)
#define BB   2
#define DD   96
#define HH   96
#define WW   96
#define CINC 16
#define COUTC 32
#define KVOL 27
#define GRID_VOX (BB*DD*HH*WW)         // 1,769,472 voxels
#define NW (KVOL*CINC*COUTC)           // 13824 weights
#define VPT 8                          // voxels per thread in compact
#define CVB (256*VPT)                  // voxels per compact block = 2048

typedef _Float16 half8 __attribute__((ext_vector_type(8)));
typedef float    floatx16 __attribute__((ext_vector_type(16)));

// ---------------- dispatch 1: scatter pids + repack weights + zero counter ---
// Weights repacked to f16 B-operand layout: wH[kk][co][ci] (ci contiguous).
__global__ __launch_bounds__(256) void setup_kernel(
        const int* __restrict__ idx, int* __restrict__ g,
        const float* __restrict__ w, _Float16* __restrict__ wH,
        int* __restrict__ counter, int n, int scatter_blocks) {
    if ((int)blockIdx.x < scatter_blocks) {
        int i = blockIdx.x * 256 + threadIdx.x;
        if (i >= n) return;
        int4 v = ((const int4*)idx)[i];   // (b, z, y, x)
        int lin = ((v.x * DD + v.y) * HH + v.z) * WW + v.w;
        g[lin] = i;
    } else {
        int t = ((int)blockIdx.x - scatter_blocks) * 256 + threadIdx.x;
        if (t == 0) counter[0] = 0;
        if (t >= NW) return;              // t = kk*512 + co*16 + ci
        int ci = t & (CINC - 1);
        int co = (t >> 4) & (COUTC - 1);
        int kk = t >> 9;
        wH[t] = (_Float16)w[(co * CINC + ci) * KVOL + kk];
    }
}

// -------- dispatch 2: block-ordered compaction + in-place grid rewrite -------
// After: g[v] = sorted id j for active voxels, n for empty. featH[j] (f16) =
// feat[perm[j]]; pc[j] = packed coords; featH[n] = zero row. Robust to ws
// garbage: entry accepted only if pid<n AND idx[pid] round-trips to voxel.
__global__ __launch_bounds__(256) void compact_kernel(
        const int* __restrict__ idx, const float* __restrict__ feat,
        int* __restrict__ g, _Float16* __restrict__ featH,
        int* __restrict__ pc, int* __restrict__ perm,
        int* __restrict__ counter, int n) {
    __shared__ int s_off[256];
    __shared__ int s_base;
    const int t = threadIdx.x;
    const int base = blockIdx.x * CVB + t * VPT;

    int4 a0 = ((const int4*)(g + base))[0];
    int4 a1 = ((const int4*)(g + base))[1];
    int vals[VPT] = {a0.x, a0.y, a0.z, a0.w, a1.x, a1.y, a1.z, a1.w};
    int pid[VPT], pck[VPT];
    int cnt = 0;
#pragma unroll
    for (int q = 0; q < VPT; ++q) {       // fully unrolled: static indices only
        int p = vals[q];
        bool ok = ((unsigned)p < (unsigned)n);
        int pk = 0;
        if (ok) {
            int4 c = ((const int4*)idx)[p];
            int lin = ((c.x * DD + c.y) * HH + c.z) * WW + c.w;
            ok = (lin == base + q);
            pk = (c.x << 21) | (c.y << 14) | (c.z << 7) | c.w;
        }
        pid[q] = ok ? p : -1;
        pck[q] = pk;
        cnt += ok ? 1 : 0;
    }

    s_off[t] = cnt;
    __syncthreads();
    for (int d = 1; d < 256; d <<= 1) {   // inclusive Hillis-Steele scan
        int v = (t >= d) ? s_off[t - d] : 0;
        __syncthreads();
        s_off[t] += v;
        __syncthreads();
    }
    if (t == 255) s_base = atomicAdd(counter, s_off[255]);
    __syncthreads();
    int o = s_base + s_off[t] - cnt;

#pragma unroll
    for (int q = 0; q < VPT; ++q) {
        int tag = n;                      // empty marker -> zero row
        int p = pid[q];
        if (p >= 0) {
            pc[o] = pck[q];
            perm[o] = p;
            const float4* src = (const float4*)(feat + (size_t)p * CINC);
            float4 f0 = src[0], f1 = src[1], f2 = src[2], f3 = src[3];
            half8 h0, h1;
            h0[0]=(_Float16)f0.x; h0[1]=(_Float16)f0.y; h0[2]=(_Float16)f0.z; h0[3]=(_Float16)f0.w;
            h0[4]=(_Float16)f1.x; h0[5]=(_Float16)f1.y; h0[6]=(_Float16)f1.z; h0[7]=(_Float16)f1.w;
            h1[0]=(_Float16)f2.x; h1[1]=(_Float16)f2.y; h1[2]=(_Float16)f2.z; h1[3]=(_Float16)f2.w;
            h1[4]=(_Float16)f3.x; h1[5]=(_Float16)f3.y; h1[6]=(_Float16)f3.z; h1[7]=(_Float16)f3.w;
            half8* dst = (half8*)(featH + (size_t)o * CINC);
            dst[0] = h0; dst[1] = h1;
            tag = o;
            ++o;
        }
        g[base + q] = tag;
    }
    if (blockIdx.x == 0 && t == 0) {      // zero row at featH[n]
        half8* zr = (half8*)(featH + (size_t)n * CINC);
        half8 hz = {};
        zr[0] = hz; zr[1] = hz;
    }
}

// ------------------------------- dispatch 3: conv (implicit GEMM) -----------
// One wave = 32 sorted points x 32 couts; 27 MFMA (32x32x16 f16), K=CIN per tap.
__global__ __launch_bounds__(256) void conv_mfma_kernel(
        const _Float16* __restrict__ featH, const int* __restrict__ pc,
        const int* __restrict__ perm, const _Float16* __restrict__ wH,
        const float* __restrict__ bias, const int* __restrict__ g,
        float* __restrict__ out, int n) {
    const int lane = threadIdx.x & 63;
    const int wave = threadIdx.x >> 6;
    const int m    = lane & 31;           // point-in-tile (A) / cout (C cols)
    const int hf   = lane >> 5;           // k-half: channels hf*8..hf*8+7
    const int j0   = (blockIdx.x * 4 + wave) * 32;
    if (j0 >= n) return;                  // n % 32 == 0: whole-wave guard only
    const int j = j0 + m;

    const int p = pc[j];
    const int x = p & 127, y = (p >> 7) & 127, z = (p >> 14) & 127, b = p >> 21;
    const int base = ((b * DD + z) * HH + y) * WW + x;
    const int pm = perm[j];               // original row for point m

    // Phase 1: probe all 27 neighbor ids (independent loads, static reg array)
    int nid[KVOL];
#pragma unroll
    for (int kk = 0; kk < KVOL; ++kk) {
        const int dz = kk / 9 - 1, dy = (kk / 3) % 3 - 1, dx = kk % 3 - 1;
        int nz = z + dz, ny = y + dy, nx = x + dx;
        bool inb = ((unsigned)nz < DD) & ((unsigned)ny < HH) & ((unsigned)nx < WW);
        int addr = inb ? base + (dz * HH + dy) * WW + dx : 0;
        int v = g[addr];
        nid[kk] = inb ? v : n;            // empty/OOB -> zero row
    }

    // Accumulator: C[row=point][col=cout]; all regs of a lane share col=m.
    float bval = bias[m];
    floatx16 acc;
#pragma unroll
    for (int i = 0; i < 16; ++i) acc[i] = bval;

    // Phase 2: 27 x (A-gather 16B + B-load 16B + MFMA)
#pragma unroll
    for (int kk = 0; kk < KVOL; ++kk) {
        half8 a = *(const half8*)(featH + (size_t)nid[kk] * CINC + hf * 8);
        half8 bf = *(const half8*)(wH + kk * (COUTC * CINC) + m * CINC + hf * 8);
        acc = __builtin_amdgcn_mfma_f32_32x32x16_f16(a, bf, acc, 0, 0, 0);
    }

    // Epilogue: reg i -> row r=(i&3)+8*(i>>2)+4*hf, col m. perm via shfl.
#pragma unroll
    for (int i = 0; i < 16; ++i) {
        int r = (i & 3) + 8 * (i >> 2) + 4 * hf;
        int row = __shfl(pm, r);          // lanes r and r+32 hold same pm
        out[(size_t)row * COUTC + m] = acc[i];   // 32 lanes = one 128B row
    }
}

extern "C" void kernel_launch(void* const* d_in, const int* in_sizes, int n_in,
                              void* d_out, int out_size, void* d_ws, size_t ws_size,
                              hipStream_t stream) {
    const float* feat  = (const float*)d_in[0];   // [N,16] fp32
    const int*   idx   = (const int*)d_in[1];     // [N,4]  int32
    const float* convw = (const float*)d_in[2];   // [32,16,3,3,3] fp32
    const float* convb = (const float*)d_in[3];   // [32] fp32
    float* out = (float*)d_out;

    const int n = in_sizes[1] / 4;                // 200000

    // workspace layout (all 16B-aligned)
    char* ws = (char*)d_ws;
    int*      g       = (int*)ws;                               // 7,077,888 B
    int*      counter = (int*)(ws + GRID_VOX * 4);              //       256 B pad
    int*      pc      = (int*)(ws + GRID_VOX * 4 + 256);        //   n*4 B
    int*      perm    = pc + n;                                 //   n*4 B
    _Float16* featH   = (_Float16*)(perm + n);                  // (n+1)*32 B
    _Float16* wH      = featH + (size_t)(n + 1) * CINC;         //  NW*2 B

    // 1) idx grid = -1 (0xFF bytes == int -1), capture-legal async memset
    hipMemsetAsync(g, 0xFF, (size_t)GRID_VOX * sizeof(int), stream);

    const int sb = (n + 255) / 256;
    const int rb = (NW + 255) / 256;
    setup_kernel<<<sb + rb, 256, 0, stream>>>(idx, g, convw, wH, counter, n, sb);
    compact_kernel<<<GRID_VOX / CVB, 256, 0, stream>>>(
        idx, feat, g, featH, pc, perm, counter, n);

    const int waves = (n + 31) / 32;              // 6250
    conv_mfma_kernel<<<(waves + 3) / 4, 256, 0, stream>>>(
        featH, pc, perm, wH, convb, g, out, n);
}

// Round 6
// 122.447 us; speedup vs baseline: 3.2623x; 1.0447x over previous
//
#include <hip/hip_runtime.h>

// Problem constants (fixed by the reference setup)
#define BB   2
#define DD   96
#define HH   96
#define WW   96
#define CINC 16
#define COUTC 32
#define KVOL 27
#define GRID_VOX (BB*DD*HH*WW)         // 1,769,472 voxels
#define NW (KVOL*CINC*COUTC)           // 13824 weights
#define VPT 8                          // voxels per thread in compact
#define CVB (256*VPT)                  // voxels per compact block = 2048
#define SWP 24                         // LDS B-row pitch in halfs (48 B: 16 data + 8 pad)

typedef _Float16 half8 __attribute__((ext_vector_type(8)));
typedef float    floatx16 __attribute__((ext_vector_type(16)));

// ---------------- dispatch 1: scatter pids + repack weights + zero counter ---
// Weights repacked to f16 B-operand layout: wH[kk][co][ci] (ci contiguous).
__global__ __launch_bounds__(256) void setup_kernel(
        const int* __restrict__ idx, int* __restrict__ g,
        const float* __restrict__ w, _Float16* __restrict__ wH,
        int* __restrict__ counter, int n, int scatter_blocks) {
    if ((int)blockIdx.x < scatter_blocks) {
        int i = blockIdx.x * 256 + threadIdx.x;
        if (i >= n) return;
        int4 v = ((const int4*)idx)[i];   // (b, z, y, x)
        int lin = ((v.x * DD + v.y) * HH + v.z) * WW + v.w;
        g[lin] = i;
    } else {
        int t = ((int)blockIdx.x - scatter_blocks) * 256 + threadIdx.x;
        if (t == 0) counter[0] = 0;
        if (t >= NW) return;              // t = kk*512 + co*16 + ci
        int ci = t & (CINC - 1);
        int co = (t >> 4) & (COUTC - 1);
        int kk = t >> 9;
        wH[t] = (_Float16)w[(co * CINC + ci) * KVOL + kk];
    }
}

// -------- dispatch 2: block-ordered compaction + in-place grid rewrite -------
// After: g[v] = sorted id j for active voxels, n for empty. featH[j] (f16) =
// feat[perm[j]]; pc[j] = packed coords; featH[n] = zero row.
// NO grid pre-init needed: an entry is accepted only if pid<n AND idx[pid]
// round-trips to this voxel — correct under arbitrary initial grid garbage
// (0xAA poison -> negative -> rejected; a stale valid pid only round-trips at
// its own voxel, where it is correct anyway). Compact rewrites every voxel.
__global__ __launch_bounds__(256) void compact_kernel(
        const int* __restrict__ idx, const float* __restrict__ feat,
        int* __restrict__ g, _Float16* __restrict__ featH,
        int* __restrict__ pc, int* __restrict__ perm,
        int* __restrict__ counter, int n) {
    __shared__ int s_wsum[4];
    __shared__ int s_wbase[4];
    __shared__ int s_base;
    const int t = threadIdx.x;
    const int lane = t & 63;
    const int wv = t >> 6;
    const int base = blockIdx.x * CVB + t * VPT;

    int4 a0 = ((const int4*)(g + base))[0];
    int4 a1 = ((const int4*)(g + base))[1];
    int vals[VPT] = {a0.x, a0.y, a0.z, a0.w, a1.x, a1.y, a1.z, a1.w};
    int pid[VPT], pck[VPT];
    int cnt = 0;
#pragma unroll
    for (int q = 0; q < VPT; ++q) {       // fully unrolled: static indices only
        int p = vals[q];
        bool ok = ((unsigned)p < (unsigned)n);
        int pk = 0;
        if (ok) {
            int4 c = ((const int4*)idx)[p];
            int lin = ((c.x * DD + c.y) * HH + c.z) * WW + c.w;
            ok = (lin == base + q);
            pk = (c.x << 21) | (c.y << 14) | (c.z << 7) | c.w;
        }
        pid[q] = ok ? p : -1;
        pck[q] = pk;
        cnt += ok ? 1 : 0;
    }

    // wave-level inclusive scan (shfl), then tiny cross-wave combine
    int incl = cnt;
#pragma unroll
    for (int d = 1; d < 64; d <<= 1) {
        int v = __shfl_up(incl, d);
        if (lane >= d) incl += v;
    }
    if (lane == 63) s_wsum[wv] = incl;
    __syncthreads();
    if (t == 0) {
        int t0 = s_wsum[0], t1 = s_wsum[1], t2 = s_wsum[2], t3 = s_wsum[3];
        s_wbase[0] = 0; s_wbase[1] = t0; s_wbase[2] = t0 + t1;
        s_wbase[3] = t0 + t1 + t2;
        s_base = atomicAdd(counter, t0 + t1 + t2 + t3);
    }
    __syncthreads();
    int o = s_base + s_wbase[wv] + incl - cnt;

#pragma unroll
    for (int q = 0; q < VPT; ++q) {
        int tag = n;                      // empty marker -> zero row
        int p = pid[q];
        if (p >= 0) {
            pc[o] = pck[q];
            perm[o] = p;
            const float4* src = (const float4*)(feat + (size_t)p * CINC);
            float4 f0 = src[0], f1 = src[1], f2 = src[2], f3 = src[3];
            half8 h0, h1;
            h0[0]=(_Float16)f0.x; h0[1]=(_Float16)f0.y; h0[2]=(_Float16)f0.z; h0[3]=(_Float16)f0.w;
            h0[4]=(_Float16)f1.x; h0[5]=(_Float16)f1.y; h0[6]=(_Float16)f1.z; h0[7]=(_Float16)f1.w;
            h1[0]=(_Float16)f2.x; h1[1]=(_Float16)f2.y; h1[2]=(_Float16)f2.z; h1[3]=(_Float16)f2.w;
            h1[4]=(_Float16)f3.x; h1[5]=(_Float16)f3.y; h1[6]=(_Float16)f3.z; h1[7]=(_Float16)f3.w;
            half8* dst = (half8*)(featH + (size_t)o * CINC);
            dst[0] = h0; dst[1] = h1;
            tag = o;
            ++o;
        }
        g[base + q] = tag;
    }
    if (blockIdx.x == 0 && t == 0) {      // zero row at featH[n]
        half8* zr = (half8*)(featH + (size_t)n * CINC);
        half8 hz = {};
        zr[0] = hz; zr[1] = hz;
    }
}

// ------------------------------- dispatch 3: conv (implicit GEMM) -----------
// One wave = 32 sorted points x 32 couts; 27 MFMA (32x32x16 f16), K=CIN/tap.
// Weights in LDS (staged once/block, 48B pitch -> worst 4-way bank conflict);
// A-gathers batched in 3 static groups of 9 to bound VGPR pressure.
__global__ __launch_bounds__(256) void conv_mfma_kernel(
        const _Float16* __restrict__ featH, const int* __restrict__ pc,
        const int* __restrict__ perm, const _Float16* __restrict__ wH,
        const float* __restrict__ bias, const int* __restrict__ g,
        float* __restrict__ out, int n) {
    __shared__ _Float16 sW[KVOL * 32 * SWP];   // 41,472 B
    const int lane = threadIdx.x & 63;
    const int wave = threadIdx.x >> 6;
    const int m    = lane & 31;           // point-in-tile (A) / cout (C cols)
    const int hf   = lane >> 5;           // k-half: channels hf*8..hf*8+7

    // Stage weights into LDS — ALL threads participate (barrier before exits).
    for (int u = threadIdx.x; u < KVOL * 64; u += 256) {
        int kk = u >> 6, r = u & 63;
        int co = r >> 1, h = r & 1;
        half8 v = *(const half8*)(wH + kk * (COUTC * CINC) + co * CINC + h * 8);
        *(half8*)(&sW[kk * 32 * SWP + co * SWP + h * 8]) = v;
    }
    __syncthreads();

    const int j0 = (blockIdx.x * 4 + wave) * 32;
    if (j0 >= n) return;                  // no barriers after this point
    const int j = j0 + m;                 // j < n (n % 32 == 0)

    const int p = pc[j];
    const int x = p & 127, y = (p >> 7) & 127, z = (p >> 14) & 127, b = p >> 21;
    const int base = ((b * DD + z) * HH + y) * WW + x;
    const int pm = perm[j];               // original row for point m

    // Phase 1: probe all 27 neighbor ids (independent loads, static reg array)
    int nid[KVOL];
#pragma unroll
    for (int kk = 0; kk < KVOL; ++kk) {
        const int dz = kk / 9 - 1, dy = (kk / 3) % 3 - 1, dx = kk % 3 - 1;
        int nz = z + dz, ny = y + dy, nx = x + dx;
        bool inb = ((unsigned)nz < DD) & ((unsigned)ny < HH) & ((unsigned)nx < WW);
        int addr = inb ? base + (dz * HH + dy) * WW + dx : 0;
        int v = g[addr];
        nid[kk] = inb ? v : n;            // empty/OOB -> zero row
    }

    // Accumulator: C[row=point][col=cout]; all regs of a lane share col=m.
    float bval = bias[m];
    floatx16 acc;
#pragma unroll
    for (int i = 0; i < 16; ++i) acc[i] = bval;

    // Phase 2: 3 groups x (9 batched A-gathers -> 9 LDS-B + MFMA)
#pragma unroll
    for (int gq = 0; gq < 3; ++gq) {
        half8 av[9];
#pragma unroll
        for (int q = 0; q < 9; ++q)
            av[q] = *(const half8*)(featH + (size_t)nid[gq * 9 + q] * CINC + hf * 8);
#pragma unroll
        for (int q = 0; q < 9; ++q) {
            const int kk = gq * 9 + q;
            half8 bf = *(const half8*)(&sW[kk * 32 * SWP + m * SWP + hf * 8]);
            acc = __builtin_amdgcn_mfma_f32_32x32x16_f16(av[q], bf, acc, 0, 0, 0);
        }
    }

    // Epilogue: reg i -> row r=(i&3)+8*(i>>2)+4*hf, col m. perm via shfl.
#pragma unroll
    for (int i = 0; i < 16; ++i) {
        int r = (i & 3) + 8 * (i >> 2) + 4 * hf;
        int row = __shfl(pm, r);          // lanes r and r+32 hold same pm
        out[(size_t)row * COUTC + m] = acc[i];   // 32 lanes = one 128B row
    }
}

extern "C" void kernel_launch(void* const* d_in, const int* in_sizes, int n_in,
                              void* d_out, int out_size, void* d_ws, size_t ws_size,
                              hipStream_t stream) {
    const float* feat  = (const float*)d_in[0];   // [N,16] fp32
    const int*   idx   = (const int*)d_in[1];     // [N,4]  int32
    const float* convw = (const float*)d_in[2];   // [32,16,3,3,3] fp32
    const float* convb = (const float*)d_in[3];   // [32] fp32
    float* out = (float*)d_out;

    const int n = in_sizes[1] / 4;                // 200000

    // workspace layout (all 16B-aligned)
    char* ws = (char*)d_ws;
    int*      g       = (int*)ws;                               // 7,077,888 B
    int*      counter = (int*)(ws + GRID_VOX * 4);              //       256 B pad
    int*      pc      = (int*)(ws + GRID_VOX * 4 + 256);        //   n*4 B
    int*      perm    = pc + n;                                 //   n*4 B
    _Float16* featH   = (_Float16*)(perm + n);                  // (n+1)*32 B
    _Float16* wH      = featH + (size_t)(n + 1) * CINC;         //  NW*2 B

    const int sb = (n + 255) / 256;
    const int rb = (NW + 255) / 256;
    setup_kernel<<<sb + rb, 256, 0, stream>>>(idx, g, convw, wH, counter, n, sb);
    compact_kernel<<<GRID_VOX / CVB, 256, 0, stream>>>(
        idx, feat, g, featH, pc, perm, counter, n);

    const int waves = (n + 31) / 32;              // 6250
    conv_mfma_kernel<<<(waves + 3) / 4, 256, 0, stream>>>(
        featH, pc, perm, wH, convb, g, out, n);
}